// Round 2
// 4699.775 us; speedup vs baseline: 1.7189x; 1.7189x over previous
//
#include <hip/hip_runtime.h>
#include <hip/hip_bf16.h>
#include <math.h>

// Problem constants
#define BB 8
#define SS 512
#define HH 768
#define NHH 12
#define DHH 64
#define LL 12
#define VV 21128
#define VVP 21248          // VV padded up to multiple of 128
#define FFF 3072
#define TT (BB*SS)         // 4096 tokens
#define PROMPT 128
#define LN_EPS 1e-12f
#define QKVN (3*HH)        // 2304

typedef __attribute__((ext_vector_type(8))) short short8;
typedef __attribute__((ext_vector_type(4))) short short4v;
typedef __attribute__((ext_vector_type(4))) float floatx4;
typedef __attribute__((ext_vector_type(16))) float floatx16;

__device__ __forceinline__ float gelu_exact(float x) {
    return 0.5f * x * (1.0f + erff(x * 0.70710678118654752f));
}

__device__ __forceinline__ short f2bs(float x) {
    __hip_bfloat16 h = __float2bfloat16(x);
    return *reinterpret_cast<short*>(&h);
}

__device__ __forceinline__ int pack2(float a, float b) {
    const unsigned int lo = (unsigned short)f2bs(a);
    const unsigned int hi = (unsigned short)f2bs(b);
    return (int)(lo | (hi << 16));
}

union I4S8 { int i[4]; short8 s; };

// async global->LDS, 16B per lane; ldsptr must be wave-uniform
__device__ __forceinline__ void load16_lds(const void* gptr, void* ldsptr) {
    __builtin_amdgcn_global_load_lds(
        (const __attribute__((address_space(1))) unsigned int*)(unsigned long long)(gptr),
        (__attribute__((address_space(3))) unsigned int*)(unsigned long long)(ldsptr),
        16, 0, 0);
}

// ---------------------------------------------------------------------------
// bf16 MFMA GEMM: C[M,N] = A[M,K] @ Bt[N,K]^T (+bias) (+gelu)
// A row-major [M,K] bf16 (K-contig), Bt row-major [Npad,K] bf16 (K-contig).
// 128x128 tile, BK=32, 256 threads = 4 waves (2x2 of 64x64), 4x4 MFMA frags.
// M % 128 == 0. N ragged allowed (epilogue guard; Bt rows padded to 128).
// ---------------------------------------------------------------------------
__global__ __launch_bounds__(256) void gemm_mfma(
    const __hip_bfloat16* __restrict__ A,
    const __hip_bfloat16* __restrict__ Bt,
    const float* __restrict__ bias,
    float* __restrict__ Cf,            // fp32 out (or null)
    __hip_bfloat16* __restrict__ Ch,   // bf16 out (or null)
    int M, int N, int K, int act)
{
    __shared__ __hip_bfloat16 As[128 * 32];   // 8 KB
    __shared__ __hip_bfloat16 Bs[128 * 32];   // 8 KB

    const int tid  = threadIdx.x;
    const int warp = tid >> 6;
    const int row0 = blockIdx.y * 128;
    const int col0 = blockIdx.x * 128;

    const int wm = warp >> 1, wn = warp & 1;
    const int lane = tid & 63;
    const int lr = lane >> 4, lc = lane & 15;

    floatx4 acc[4][4] = {};

    // staging map: seg = tid + p*256; row = seg/4; col8 = (seg%4)*8
    const int sRow = tid >> 2;
    const int sCol = (tid & 3) << 3;
    const __hip_bfloat16* aG0 = A  + (size_t)(row0 + sRow)      * K + sCol;
    const __hip_bfloat16* aG1 = A  + (size_t)(row0 + sRow + 64) * K + sCol;
    const __hip_bfloat16* bG0 = Bt + (size_t)(col0 + sRow)      * K + sCol;
    const __hip_bfloat16* bG1 = Bt + (size_t)(col0 + sRow + 64) * K + sCol;

    char* aL = (char*)As + warp * 1024;
    char* bL = (char*)Bs + warp * 1024;

    for (int k0 = 0; k0 < K; k0 += 32) {
        load16_lds(aG0 + k0, aL);
        load16_lds(aG1 + k0, aL + 4096);
        load16_lds(bG0 + k0, bL);
        load16_lds(bG1 + k0, bL + 4096);
        __syncthreads();

        short8 af[4], bf[4];
        #pragma unroll
        for (int mt = 0; mt < 4; ++mt)
            af[mt] = *(const short8*)((const char*)As + (((wm * 64 + mt * 16 + lc) * 32) + lr * 8) * 2);
        #pragma unroll
        for (int nt = 0; nt < 4; ++nt)
            bf[nt] = *(const short8*)((const char*)Bs + (((wn * 64 + nt * 16 + lc) * 32) + lr * 8) * 2);

        #pragma unroll
        for (int mt = 0; mt < 4; ++mt)
            #pragma unroll
            for (int nt = 0; nt < 4; ++nt)
                acc[mt][nt] = __builtin_amdgcn_mfma_f32_16x16x32_bf16(
                    af[mt], bf[nt], acc[mt][nt], 0, 0, 0);
        __syncthreads();
    }

    #pragma unroll
    for (int mt = 0; mt < 4; ++mt) {
        #pragma unroll
        for (int nt = 0; nt < 4; ++nt) {
            const int n = col0 + wn * 64 + nt * 16 + lc;
            if (n < N) {
                #pragma unroll
                for (int r = 0; r < 4; ++r) {
                    const int m = row0 + wm * 64 + mt * 16 + lr * 4 + r;
                    float v = acc[mt][nt][r];
                    if (bias) v += bias[n];
                    if (act)  v = gelu_exact(v);
                    if (Cf) Cf[(size_t)m * N + n] = v;
                    if (Ch) Ch[(size_t)m * N + n] = __float2bfloat16(v);
                }
            }
        }
    }
}

// ---------------------------------------------------------------------------
// fp32 -> bf16 transpose: out[z][row_off + n][k] = (bf16) W[z][k][n]
// ---------------------------------------------------------------------------
__global__ void transpose_cvt(
    const float* __restrict__ W, __hip_bfloat16* __restrict__ out,
    int K, int N, long long in_lstride, long long out_lstride,
    int row_off, int out_ld)
{
    __shared__ float t[32][33];
    const int n0 = blockIdx.x * 32;
    const int k0 = blockIdx.y * 32;
    const int z  = blockIdx.z;
    const int tx = threadIdx.x, ty = threadIdx.y;

    const float* Wz = W + (size_t)z * in_lstride;
    __hip_bfloat16* Oz = out + (size_t)z * out_lstride;

    #pragma unroll
    for (int r = 0; r < 4; ++r) {
        const int k = k0 + ty + r * 8;
        const int n = n0 + tx;
        if (k < K && n < N) t[ty + r * 8][tx] = Wz[(size_t)k * N + n];
    }
    __syncthreads();
    #pragma unroll
    for (int r = 0; r < 4; ++r) {
        const int n = n0 + ty + r * 8;
        const int k = k0 + tx;
        if (n < N && k < K)
            Oz[(size_t)(row_off + n) * out_ld + k] = __float2bfloat16(t[tx][ty + r * 8]);
    }
}

__global__ void concat_bias(const float* __restrict__ bq, const float* __restrict__ bk,
                            const float* __restrict__ bv, float* __restrict__ bqkv)
{
    const int i = blockIdx.x * 256 + threadIdx.x;
    if (i >= LL * QKVN) return;
    const int l = i / QKVN, j = i % QKVN;
    float v;
    if (j < HH)            v = bq[l * HH + j];
    else if (j < 2 * HH)   v = bk[l * HH + j - HH];
    else                   v = bv[l * HH + j - 2 * HH];
    bqkv[i] = v;
}

// ---------------------------------------------------------------------------
// Embedding + LayerNorm -> bf16 h
// ---------------------------------------------------------------------------
__global__ __launch_bounds__(256) void embed_ln(
    const int* __restrict__ ids, const float* __restrict__ we,
    const float* __restrict__ pe, const float* __restrict__ te,
    const float* __restrict__ g, const float* __restrict__ b,
    __hip_bfloat16* __restrict__ h)
{
    const int t = blockIdx.x;
    const int s = t & (SS - 1);
    const int tid = threadIdx.x;
    __shared__ float x[HH];
    __shared__ float red[256];

    const int id = ids[t];
    for (int j = tid; j < HH; j += 256)
        x[j] = we[(size_t)id * HH + j] + pe[(size_t)s * HH + j] + te[j];
    __syncthreads();

    float sum = x[tid] + x[tid + 256] + x[tid + 512];
    red[tid] = sum; __syncthreads();
    for (int s2 = 128; s2 > 0; s2 >>= 1) { if (tid < s2) red[tid] += red[tid + s2]; __syncthreads(); }
    const float mean = red[0] * (1.0f / HH);
    __syncthreads();

    const float c0 = x[tid] - mean, c1 = x[tid + 256] - mean, c2 = x[tid + 512] - mean;
    red[tid] = c0 * c0 + c1 * c1 + c2 * c2; __syncthreads();
    for (int s2 = 128; s2 > 0; s2 >>= 1) { if (tid < s2) red[tid] += red[tid + s2]; __syncthreads(); }
    const float inv = rsqrtf(red[0] * (1.0f / HH) + LN_EPS);

    h[(size_t)t * HH + tid      ] = __float2bfloat16(c0 * inv * g[tid      ] + b[tid      ]);
    h[(size_t)t * HH + tid + 256] = __float2bfloat16(c1 * inv * g[tid + 256] + b[tid + 256]);
    h[(size_t)t * HH + tid + 512] = __float2bfloat16(c2 * inv * g[tid + 512] + b[tid + 512]);
}

// ---------------------------------------------------------------------------
// Residual(bf16) + y(fp32) -> LayerNorm -> bf16 (in-place safe per-row)
// ---------------------------------------------------------------------------
__global__ __launch_bounds__(256) void add_ln(
    const __hip_bfloat16* __restrict__ resid, const float* __restrict__ y,
    const float* __restrict__ g, const float* __restrict__ b,
    __hip_bfloat16* __restrict__ hout)
{
    const int t = blockIdx.x;
    const int tid = threadIdx.x;
    __shared__ float x[HH];
    __shared__ float red[256];

    for (int j = tid; j < HH; j += 256)
        x[j] = __bfloat162float(resid[(size_t)t * HH + j]) + y[(size_t)t * HH + j];
    __syncthreads();

    float sum = x[tid] + x[tid + 256] + x[tid + 512];
    red[tid] = sum; __syncthreads();
    for (int s2 = 128; s2 > 0; s2 >>= 1) { if (tid < s2) red[tid] += red[tid + s2]; __syncthreads(); }
    const float mean = red[0] * (1.0f / HH);
    __syncthreads();

    const float c0 = x[tid] - mean, c1 = x[tid + 256] - mean, c2 = x[tid + 512] - mean;
    red[tid] = c0 * c0 + c1 * c1 + c2 * c2; __syncthreads();
    for (int s2 = 128; s2 > 0; s2 >>= 1) { if (tid < s2) red[tid] += red[tid + s2]; __syncthreads(); }
    const float inv = rsqrtf(red[0] * (1.0f / HH) + LN_EPS);

    hout[(size_t)t * HH + tid      ] = __float2bfloat16(c0 * inv * g[tid      ] + b[tid      ]);
    hout[(size_t)t * HH + tid + 256] = __float2bfloat16(c1 * inv * g[tid + 256] + b[tid + 256]);
    hout[(size_t)t * HH + tid + 512] = __float2bfloat16(c2 * inv * g[tid + 512] + b[tid + 512]);
}

// ---------------------------------------------------------------------------
// MFMA flash attention.
// Block = 256 threads = 4 waves; each wave owns 32 queries (q0 = qb + wid*32).
// Per 64-key tile:
//   - K staged row-major bf16 in LDS [64][64], XOR-swizzled (byte ^= (key&7)<<4)
//   - V staged TRANSPOSED bf16 in LDS Vt[d][key], XOR-swizzled (byte ^= (d&7)<<4)
//   - S^T = mfma_32x32x16(K, Q): D[key][q], col = lane&31 = own q (swapped trick:
//     softmax reduction is in-lane + one shfl_xor(32))
//   - P^T -> bf16 B-fragments via pack2 + 4 shfl_xor(32) per k-slice
//   - O^T = mfma_32x32x16(Vt, P^T): D[dim][q], col = own q -> corr rescale in-lane
// Frag conventions (gfx950, verified D-layout m74/m101; A/B by the GEMM pattern):
//   A: lane holds A[l&31][(l>>5)*8 + j]   B: lane holds B[(l>>5)*8 + j][l&31]
//   D: col = l&31, row = (r&3) + 8*(r>>2) + 4*(l>>5)
// ---------------------------------------------------------------------------
__global__ __launch_bounds__(256) void attn_mfma(
    const float* __restrict__ qkv, __hip_bfloat16* __restrict__ ctx)
{
    const int qb  = blockIdx.x * 128;
    const int hh  = blockIdx.y;
    const int b   = blockIdx.z;
    const int tid = threadIdx.x;
    const int wid = tid >> 6;
    const int lane = tid & 63;
    const int lq = lane & 31;     // this lane's query column
    const int w  = lane >> 5;     // half-select

    __shared__ __hip_bfloat16 Kb[64 * 64];   // [key][d] swizzled, 8 KB
    __shared__ __hip_bfloat16 Vt[64 * 64];   // [d][key] swizzled, 8 KB

    const int q0 = qb + wid * 32;
    const int i  = q0 + lq;

    // ---- Q fragments, pre-scaled by 1/8: qf[kt][j] = Q[i][kt*16 + w*8 + j]
    short8 qf[4];
    {
        const float* qrow = qkv + (size_t)(b * SS + i) * QKVN + hh * DHH;
        #pragma unroll
        for (int kt = 0; kt < 4; ++kt) {
            const float4 x0 = *(const float4*)(qrow + kt * 16 + w * 8);
            const float4 x1 = *(const float4*)(qrow + kt * 16 + w * 8 + 4);
            short8 q8;
            q8[0] = f2bs(x0.x * 0.125f); q8[1] = f2bs(x0.y * 0.125f);
            q8[2] = f2bs(x0.z * 0.125f); q8[3] = f2bs(x0.w * 0.125f);
            q8[4] = f2bs(x1.x * 0.125f); q8[5] = f2bs(x1.y * 0.125f);
            q8[6] = f2bs(x1.z * 0.125f); q8[7] = f2bs(x1.w * 0.125f);
            qf[kt] = q8;
        }
    }

    floatx16 acc_o[2] = {};          // O^T accum: row = dim (mtd*32 + rm), col = own q
    float m_run = -1e30f, l_run = 0.f;

    // staging index maps (all 256 threads)
    const int skey = tid >> 2;           // K: key row 0..63
    const int sd4  = (tid & 3) << 2;     // K: dim base {0,4,8,12}, +16x per step
    const int vd   = tid & 63;           // V: dim (row of Vt)
    const int vk0  = (tid >> 6) << 4;    // V: key base {0,16,32,48}

    const int kmax = (qb + 128 > PROMPT) ? (qb + 128) : PROMPT;

    for (int j0 = 0; j0 < kmax; j0 += 64) {
        // ---- stage K tile: coalesced dwordx4 loads, swizzled b64 LDS writes
        {
            const float* kg = qkv + (size_t)(b * SS + j0 + skey) * QKVN + HH + hh * DHH;
            char* krow = (char*)Kb + skey * 128;
            const int sw = (skey & 7) << 4;
            #pragma unroll
            for (int x = 0; x < 4; ++x) {
                const float4 f = *(const float4*)(kg + sd4 + 16 * x);
                short4v kv;
                kv[0] = f2bs(f.x); kv[1] = f2bs(f.y); kv[2] = f2bs(f.z); kv[3] = f2bs(f.w);
                *(short4v*)(krow + (((sd4 << 1) + (x << 5)) ^ sw)) = kv;
            }
        }
        // ---- stage V tile transposed: coalesced scalar loads (lane = dim),
        //      contiguous swizzled b128 LDS writes along keys
        {
            const float* vg = qkv + (size_t)(b * SS + j0 + vk0) * QKVN + 2 * HH + hh * DHH + vd;
            char* vrow = (char*)Vt + vd * 128;
            const int sw = (vd & 7) << 4;
            short8 v8a, v8b;
            #pragma unroll
            for (int x = 0; x < 8; ++x) v8a[x] = f2bs(vg[(size_t)x * QKVN]);
            #pragma unroll
            for (int x = 0; x < 8; ++x) v8b[x] = f2bs(vg[(size_t)(x + 8) * QKVN]);
            *(short8*)(vrow + ((vk0 << 1) ^ sw))        = v8a;
            *(short8*)(vrow + (((vk0 << 1) + 16) ^ sw)) = v8b;
        }
        __syncthreads();

        // ---- S^T = K x Q^T : s_acc[mt] covers keys mt*32..+31 for own q
        floatx16 s_acc[2];
        #pragma unroll
        for (int mt = 0; mt < 2; ++mt) {
            const char* krow = (const char*)Kb + (mt * 32 + lq) * 128;
            const int sw = (lq & 7) << 4;
            floatx16 acc = {};
            #pragma unroll
            for (int kt = 0; kt < 4; ++kt) {
                const short8 kf = *(const short8*)(krow + ((kt * 32 + w * 16) ^ sw));
                acc = __builtin_amdgcn_mfma_f32_32x32x16_bf16(kf, qf[kt], acc, 0, 0, 0);
            }
            s_acc[mt] = acc;
        }

        // ---- prefix-LM mask (element key index: j0 + mt*32 + (r&3) + 8*(r>>2) + 4w)
        const bool tfull = ((j0 + 63) < PROMPT) || ((j0 + 63) <= q0);
        if (!tfull) {
            #pragma unroll
            for (int mt = 0; mt < 2; ++mt)
                #pragma unroll
                for (int r = 0; r < 16; ++r) {
                    const int key = j0 + mt * 32 + (r & 3) + ((r >> 2) << 3) + (w << 2);
                    if (key >= PROMPT && key > i) s_acc[mt][r] = -1e30f;
                }
        }

        // ---- online softmax (own 32 values + partner half via shfl_xor(32))
        float tmax = -1e30f;
        #pragma unroll
        for (int mt = 0; mt < 2; ++mt)
            #pragma unroll
            for (int r = 0; r < 16; ++r) tmax = fmaxf(tmax, s_acc[mt][r]);
        tmax = fmaxf(tmax, __shfl_xor(tmax, 32, 64));
        const float mnew = fmaxf(m_run, tmax);
        const float corr = __expf(m_run - mnew);
        m_run = mnew;
        float psum = 0.f;
        #pragma unroll
        for (int mt = 0; mt < 2; ++mt)
            #pragma unroll
            for (int r = 0; r < 16; ++r) {
                const float p = __expf(s_acc[mt][r] - mnew);
                s_acc[mt][r] = p;
                psum += p;
            }
        l_run = l_run * corr + psum;    // per-half-lane sum; combined at end
        #pragma unroll
        for (int r = 0; r < 16; ++r) { acc_o[0][r] *= corr; acc_o[1][r] *= corr; }

        // ---- P^T -> bf16 B-fragments: pbf[kt][j] = P[key = kt*16 + w*8 + j][own q]
        short8 pbf[4];
        #pragma unroll
        for (int kt = 0; kt < 4; ++kt) {
            const int mt = kt >> 1;
            const int c0 = ((2 * kt) & 3) << 2;
            const int c1 = ((2 * kt + 1) & 3) << 2;
            const int w0 = pack2(s_acc[mt][c0 + 0], s_acc[mt][c0 + 1]);
            const int w1 = pack2(s_acc[mt][c0 + 2], s_acc[mt][c0 + 3]);
            const int w2 = pack2(s_acc[mt][c1 + 0], s_acc[mt][c1 + 1]);
            const int w3 = pack2(s_acc[mt][c1 + 2], s_acc[mt][c1 + 3]);
            const int t0 = __shfl_xor(w0, 32, 64);
            const int t1 = __shfl_xor(w1, 32, 64);
            const int t2 = __shfl_xor(w2, 32, 64);
            const int t3 = __shfl_xor(w3, 32, 64);
            I4S8 u;
            u.i[0] = w ? t2 : w0;
            u.i[1] = w ? t3 : w1;
            u.i[2] = w ? w2 : t0;
            u.i[3] = w ? w3 : t1;
            pbf[kt] = u.s;
        }

        // ---- O^T += Vt x P^T
        #pragma unroll
        for (int mtd = 0; mtd < 2; ++mtd) {
            const char* vrow = (const char*)Vt + (mtd * 32 + lq) * 128;
            const int sw = (lq & 7) << 4;
            #pragma unroll
            for (int kt = 0; kt < 4; ++kt) {
                const short8 vf = *(const short8*)(vrow + ((kt * 32 + w * 16) ^ sw));
                acc_o[mtd] = __builtin_amdgcn_mfma_f32_32x32x16_bf16(vf, pbf[kt], acc_o[mtd], 0, 0, 0);
            }
        }
        __syncthreads();
    }

    // ---- epilogue: combine halves, normalize, store (dims 4-contiguous per chunk)
    const float lt  = l_run + __shfl_xor(l_run, 32, 64);
    const float inv = 1.0f / lt;
    __hip_bfloat16* crow = ctx + (size_t)(b * SS + i) * HH + hh * DHH;
    #pragma unroll
    for (int mtd = 0; mtd < 2; ++mtd)
        #pragma unroll
        for (int rq = 0; rq < 4; ++rq) {
            short4v o4;
            #pragma unroll
            for (int e = 0; e < 4; ++e)
                o4[e] = f2bs(acc_o[mtd][rq * 4 + e] * inv);
            *(short4v*)(crow + mtd * 32 + rq * 8 + w * 4) = o4;
        }
}

// ---------------------------------------------------------------------------
// CE over one batch-chunk of logits (384 rows)
// ---------------------------------------------------------------------------
__global__ __launch_bounds__(256) void ce_kernel(
    const float* __restrict__ logits, const int* __restrict__ labels,
    int bidx, float* __restrict__ acc)
{
    const int r = blockIdx.x;
    const int t = bidx * SS + PROMPT + r;
    const float* row = logits + (size_t)r * VV;
    const int tid = threadIdx.x;
    __shared__ float red[256];

    float mx = -1e30f;
    for (int c = tid; c < VV; c += 256) mx = fmaxf(mx, row[c]);
    red[tid] = mx; __syncthreads();
    for (int s2 = 128; s2 > 0; s2 >>= 1) { if (tid < s2) red[tid] = fmaxf(red[tid], red[tid + s2]); __syncthreads(); }
    mx = red[0];
    __syncthreads();

    float se = 0.f;
    for (int c = tid; c < VV; c += 256) se += __expf(row[c] - mx);
    red[tid] = se; __syncthreads();
    for (int s2 = 128; s2 > 0; s2 >>= 1) { if (tid < s2) red[tid] += red[tid + s2]; __syncthreads(); }

    if (tid == 0) {
        const int lab = labels[t];
        if (lab >= 0) {
            const float nll = -(row[lab] - mx - logf(red[0]));
            atomicAdd(&acc[0], nll);
            atomicAdd(&acc[1], 1.0f);
        }
    }
}

__global__ void finalize_kernel(const float* __restrict__ acc, float* __restrict__ out)
{
    out[0] = (acc[1] > 0.f) ? acc[0] / acc[1] : 0.f;
}

// ---------------------------------------------------------------------------
extern "C" void kernel_launch(void* const* d_in, const int* in_sizes, int n_in,
                              void* d_out, int out_size, void* d_ws, size_t ws_size,
                              hipStream_t stream)
{
    const int*   input_ids = (const int*)  d_in[0];
    const int*   labels    = (const int*)  d_in[1];
    const float* word_emb  = (const float*)d_in[2];
    const float* pos_emb   = (const float*)d_in[3];
    const float* type_emb  = (const float*)d_in[4];
    const float* emb_ln_g  = (const float*)d_in[5];
    const float* emb_ln_b  = (const float*)d_in[6];
    const float* Wq = (const float*)d_in[7];   const float* bq = (const float*)d_in[8];
    const float* Wk = (const float*)d_in[9];   const float* bk = (const float*)d_in[10];
    const float* Wv = (const float*)d_in[11];  const float* bv = (const float*)d_in[12];
    const float* Wo = (const float*)d_in[13];  const float* bo = (const float*)d_in[14];
    const float* ln1_g = (const float*)d_in[15]; const float* ln1_b = (const float*)d_in[16];
    const float* W1 = (const float*)d_in[17];  const float* bf1 = (const float*)d_in[18];
    const float* W2 = (const float*)d_in[19];  const float* bf2 = (const float*)d_in[20];
    const float* ln2_g = (const float*)d_in[21]; const float* ln2_b = (const float*)d_in[22];
    const float* Wc = (const float*)d_in[23];  const float* bc = (const float*)d_in[24];

    // ---- workspace layout (fp32 first, then bf16) ----
    float* fws = (float*)d_ws;
    float* qkv  = fws;                        // 4096*2304 = 9,437,184 f
    float* lg   = qkv;                        // alias: 384*21128 = 8,113,152 f < qkv size
    float* tmp  = qkv + (size_t)TT * QKVN;    // 4096*768
    float* bqkv = tmp + (size_t)TT * HH;      // 12*2304
    float* acc  = bqkv + (size_t)LL * QKVN;   // 2 (+pad)

    __hip_bfloat16* bws = (__hip_bfloat16*)(acc + 8);
    __hip_bfloat16* h    = bws;                                   // 4096*768
    __hip_bfloat16* ctx  = h    + (size_t)TT * HH;                // 4096*768
    __hip_bfloat16* ff1  = ctx  + (size_t)TT * HH;                // 4096*3072
    __hip_bfloat16* qkvw = ff1  + (size_t)TT * FFF;               // 12*2304*768
    __hip_bfloat16* wot  = qkvw + (size_t)LL * QKVN * HH;         // 12*768*768
    __hip_bfloat16* w1t  = wot  + (size_t)LL * HH * HH;           // 12*3072*768
    __hip_bfloat16* w2t  = w1t  + (size_t)LL * FFF * HH;          // 12*768*3072
    __hip_bfloat16* wct  = w2t  + (size_t)LL * HH * FFF;          // 21248*768

    hipMemsetAsync(acc, 0, 2 * sizeof(float), stream);

    // ---- weight convert + transpose (bf16, K-contiguous) ----
    const dim3 tb(32, 8);
    transpose_cvt<<<dim3(24, 24, LL), tb, 0, stream>>>(Wq, qkvw, HH, HH,
        (long long)HH * HH, (long long)QKVN * HH, 0, HH);
    transpose_cvt<<<dim3(24, 24, LL), tb, 0, stream>>>(Wk, qkvw, HH, HH,
        (long long)HH * HH, (long long)QKVN * HH, HH, HH);
    transpose_cvt<<<dim3(24, 24, LL), tb, 0, stream>>>(Wv, qkvw, HH, HH,
        (long long)HH * HH, (long long)QKVN * HH, 2 * HH, HH);
    transpose_cvt<<<dim3(24, 24, LL), tb, 0, stream>>>(Wo, wot, HH, HH,
        (long long)HH * HH, (long long)HH * HH, 0, HH);
    transpose_cvt<<<dim3(96, 24, LL), tb, 0, stream>>>(W1, w1t, HH, FFF,
        (long long)HH * FFF, (long long)FFF * HH, 0, HH);
    transpose_cvt<<<dim3(24, 96, LL), tb, 0, stream>>>(W2, w2t, FFF, HH,
        (long long)FFF * HH, (long long)HH * FFF, 0, FFF);
    transpose_cvt<<<dim3(661, 24, 1), tb, 0, stream>>>(Wc, wct, HH, VV,
        0, 0, 0, HH);
    concat_bias<<<(LL * QKVN + 255) / 256, 256, 0, stream>>>(bq, bk, bv, bqkv);

    // ---- embeddings ----
    embed_ln<<<TT, 256, 0, stream>>>(input_ids, word_emb, pos_emb, type_emb,
                                     emb_ln_g, emb_ln_b, h);

    const dim3 gQKV(QKVN / 128, TT / 128);   // 18 x 32
    const dim3 gH(HH / 128, TT / 128);       // 6 x 32
    const dim3 gF(FFF / 128, TT / 128);      // 24 x 32
    const dim3 gAttn(SS / 128, NHH, BB);     // 4 x 12 x 8

    for (int l = 0; l < LL; ++l) {
        gemm_mfma<<<gQKV, 256, 0, stream>>>(h, qkvw + (size_t)l * QKVN * HH,
            bqkv + (size_t)l * QKVN, qkv, nullptr, TT, QKVN, HH, 0);

        attn_mfma<<<gAttn, 256, 0, stream>>>(qkv, ctx);

        gemm_mfma<<<gH, 256, 0, stream>>>(ctx, wot + (size_t)l * HH * HH,
            bo + (size_t)l * HH, tmp, nullptr, TT, HH, HH, 0);
        add_ln<<<TT, 256, 0, stream>>>(h, tmp, ln1_g + (size_t)l * HH, ln1_b + (size_t)l * HH, h);

        gemm_mfma<<<gF, 256, 0, stream>>>(h, w1t + (size_t)l * FFF * HH,
            bf1 + (size_t)l * FFF, nullptr, ff1, TT, FFF, HH, 1);
        gemm_mfma<<<gH, 256, 0, stream>>>(ff1, w2t + (size_t)l * HH * FFF,
            bf2 + (size_t)l * HH, tmp, nullptr, TT, HH, FFF, 0);
        add_ln<<<TT, 256, 0, stream>>>(h, tmp, ln2_g + (size_t)l * HH, ln2_b + (size_t)l * HH, h);
    }

    // ---- LM head + CE per batch (only s >= PROMPT rows) ----
    const int Mchunk = SS - PROMPT;              // 384
    const dim3 gV(VVP / 128, Mchunk / 128);      // 166 x 3
    for (int b = 0; b < BB; ++b) {
        const __hip_bfloat16* Arow = h + (size_t)(b * SS + PROMPT) * HH;
        gemm_mfma<<<gV, 256, 0, stream>>>(Arow, wct, bc, lg, nullptr, Mchunk, VV, HH, 0);
        ce_kernel<<<Mchunk, 256, 0, stream>>>(lg, labels, b, acc);
    }

    finalize_kernel<<<1, 1, 0, stream>>>(acc, (float*)d_out);
}

// Round 3
// 4422.140 us; speedup vs baseline: 1.8268x; 1.0628x over previous
//
#include <hip/hip_runtime.h>
#include <hip/hip_bf16.h>
#include <math.h>

// Problem constants
#define BB 8
#define SS 512
#define HH 768
#define NHH 12
#define DHH 64
#define LL 12
#define VV 21128
#define VVP 21248          // VV padded up to multiple of 128
#define FFF 3072
#define TT (BB*SS)         // 4096 tokens
#define PROMPT 128
#define LN_EPS 1e-12f
#define QKVN (3*HH)        // 2304

typedef __attribute__((ext_vector_type(8))) short short8;
typedef __attribute__((ext_vector_type(4))) short short4v;
typedef __attribute__((ext_vector_type(4))) float floatx4;
typedef __attribute__((ext_vector_type(16))) float floatx16;

__device__ __forceinline__ float gelu_exact(float x) {
    return 0.5f * x * (1.0f + erff(x * 0.70710678118654752f));
}

__device__ __forceinline__ short f2bs(float x) {
    __hip_bfloat16 h = __float2bfloat16(x);
    return *reinterpret_cast<short*>(&h);
}

__device__ __forceinline__ int pack2(float a, float b) {
    const unsigned int lo = (unsigned short)f2bs(a);
    const unsigned int hi = (unsigned short)f2bs(b);
    return (int)(lo | (hi << 16));
}

union I4S8 { int i[4]; short8 s; };

// async global->LDS, 16B per lane; ldsptr must be wave-uniform
__device__ __forceinline__ void load16_lds(const void* gptr, void* ldsptr) {
    __builtin_amdgcn_global_load_lds(
        (const __attribute__((address_space(1))) unsigned int*)(unsigned long long)(gptr),
        (__attribute__((address_space(3))) unsigned int*)(unsigned long long)(ldsptr),
        16, 0, 0);
}

// ---------------------------------------------------------------------------
// bf16 MFMA GEMM: C[M,N] = A[M,K] @ Bt[N,K]^T (+bias) (+gelu)
// A row-major [M,K] bf16, Bt row-major [Npad,K] bf16. 128x128 tile, BK=64,
// 256 threads = 4 waves (2x2 of 64x64), 4x4 MFMA frags per wave.
// LDS tiles [128][64] bf16 (128B rows) with chunk XOR-swizzle: logical 16B
// chunk (row, c) lives at LDS slot (row, c ^ (row&7)). Staging keeps LDS
// linear (global_load_lds) and pre-swizzles the GLOBAL source chunk instead
// (same involution). ds_read_b128 per 16-lane phase then covers all 32
// banks at 2 lanes/bank (conflict-free).
// Split-K: gridDim.z = P chunks; each writes fp32 partial Cf + z*M*N
// (caller passes bias=null, act=0, Ch=null when P>1).
// M % 128 == 0, K % (64*P) == 0. N ragged allowed (epilogue guard).
// ---------------------------------------------------------------------------
__global__ __launch_bounds__(256) void gemm_mfma(
    const __hip_bfloat16* __restrict__ A,
    const __hip_bfloat16* __restrict__ Bt,
    const float* __restrict__ bias,
    float* __restrict__ Cf,            // fp32 out (or null)
    __hip_bfloat16* __restrict__ Ch,   // bf16 out (or null)
    int M, int N, int K, int act)
{
    __shared__ __hip_bfloat16 As[128 * 64];   // 16 KB
    __shared__ __hip_bfloat16 Bs[128 * 64];   // 16 KB

    const int tid  = threadIdx.x;
    const int wid  = tid >> 6;
    const int lane = tid & 63;
    const int row0 = blockIdx.y * 128;
    const int col0 = blockIdx.x * 128;

    const int wm = wid >> 1, wn = wid & 1;
    const int lr = lane >> 4, lc = lane & 15;

    // split-K
    const int nz   = gridDim.z;
    const int Kc   = K / nz;
    const int kbeg = blockIdx.z * Kc;
    if (nz > 1) Cf += (size_t)blockIdx.z * M * N;

    floatx4 acc[4][4] = {};

    // staging map: chunk units of 16B (8 bf16). seg = p*256 + tid.
    // row = p*32 + (tid>>3), logical chunk c = tid&7, source chunk = c ^ (row&7).
    const int sRow = tid >> 3;                  // 0..31 (+32 per p)
    const int sC   = (tid & 7) ^ (sRow & 7);    // pre-swizzled source chunk
    const __hip_bfloat16* aG[4];
    const __hip_bfloat16* bG[4];
    #pragma unroll
    for (int p = 0; p < 4; ++p) {
        aG[p] = A  + (size_t)(row0 + p * 32 + sRow) * K + kbeg + sC * 8;
        bG[p] = Bt + (size_t)(col0 + p * 32 + sRow) * K + kbeg + sC * 8;
    }
    char* aDst = (char*)As + wid * 1024;
    char* bDst = (char*)Bs + wid * 1024;

    for (int k0 = 0; k0 < Kc; k0 += 64) {
        #pragma unroll
        for (int p = 0; p < 4; ++p) {
            load16_lds(aG[p] + k0, aDst + p * 4096);
            load16_lds(bG[p] + k0, bDst + p * 4096);
        }
        __syncthreads();

        #pragma unroll
        for (int ks = 0; ks < 2; ++ks) {
            short8 af[4], bfr[4];
            #pragma unroll
            for (int mt = 0; mt < 4; ++mt) {
                const int row = wm * 64 + mt * 16 + lc;
                af[mt] = *(const short8*)((const char*)As + row * 128 +
                         ((((ks << 2) | lr) ^ (row & 7)) << 4));
            }
            #pragma unroll
            for (int nt = 0; nt < 4; ++nt) {
                const int row = wn * 64 + nt * 16 + lc;
                bfr[nt] = *(const short8*)((const char*)Bs + row * 128 +
                          ((((ks << 2) | lr) ^ (row & 7)) << 4));
            }
            #pragma unroll
            for (int mt = 0; mt < 4; ++mt)
                #pragma unroll
                for (int nt = 0; nt < 4; ++nt)
                    acc[mt][nt] = __builtin_amdgcn_mfma_f32_16x16x32_bf16(
                        af[mt], bfr[nt], acc[mt][nt], 0, 0, 0);
        }
        __syncthreads();
    }

    #pragma unroll
    for (int mt = 0; mt < 4; ++mt) {
        #pragma unroll
        for (int nt = 0; nt < 4; ++nt) {
            const int n = col0 + wn * 64 + nt * 16 + lc;
            if (n < N) {
                #pragma unroll
                for (int r = 0; r < 4; ++r) {
                    const int m = row0 + wm * 64 + mt * 16 + lr * 4 + r;
                    float v = acc[mt][nt][r];
                    if (bias) v += bias[n];
                    if (act)  v = gelu_exact(v);
                    if (Cf) Cf[(size_t)m * N + n] = v;
                    if (Ch) Ch[(size_t)m * N + n] = __float2bfloat16(v);
                }
            }
        }
    }
}

// ---------------------------------------------------------------------------
// fp32 -> bf16 transpose: out[z][row_off + n][k] = (bf16) W[z][k][n]
// ---------------------------------------------------------------------------
__global__ void transpose_cvt(
    const float* __restrict__ W, __hip_bfloat16* __restrict__ out,
    int K, int N, long long in_lstride, long long out_lstride,
    int row_off, int out_ld)
{
    __shared__ float t[32][33];
    const int n0 = blockIdx.x * 32;
    const int k0 = blockIdx.y * 32;
    const int z  = blockIdx.z;
    const int tx = threadIdx.x, ty = threadIdx.y;

    const float* Wz = W + (size_t)z * in_lstride;
    __hip_bfloat16* Oz = out + (size_t)z * out_lstride;

    #pragma unroll
    for (int r = 0; r < 4; ++r) {
        const int k = k0 + ty + r * 8;
        const int n = n0 + tx;
        if (k < K && n < N) t[ty + r * 8][tx] = Wz[(size_t)k * N + n];
    }
    __syncthreads();
    #pragma unroll
    for (int r = 0; r < 4; ++r) {
        const int n = n0 + ty + r * 8;
        const int k = k0 + tx;
        if (n < N && k < K)
            Oz[(size_t)(row_off + n) * out_ld + k] = __float2bfloat16(t[tx][ty + r * 8]);
    }
}

__global__ void concat_bias(const float* __restrict__ bq, const float* __restrict__ bk,
                            const float* __restrict__ bv, float* __restrict__ bqkv)
{
    const int i = blockIdx.x * 256 + threadIdx.x;
    if (i >= LL * QKVN) return;
    const int l = i / QKVN, j = i % QKVN;
    float v;
    if (j < HH)            v = bq[l * HH + j];
    else if (j < 2 * HH)   v = bk[l * HH + j - HH];
    else                   v = bv[l * HH + j - 2 * HH];
    bqkv[i] = v;
}

// ---------------------------------------------------------------------------
// Embedding + LayerNorm -> bf16 h
// ---------------------------------------------------------------------------
__global__ __launch_bounds__(256) void embed_ln(
    const int* __restrict__ ids, const float* __restrict__ we,
    const float* __restrict__ pe, const float* __restrict__ te,
    const float* __restrict__ g, const float* __restrict__ b,
    __hip_bfloat16* __restrict__ h)
{
    const int t = blockIdx.x;
    const int s = t & (SS - 1);
    const int tid = threadIdx.x;
    __shared__ float x[HH];
    __shared__ float red[256];

    const int id = ids[t];
    for (int j = tid; j < HH; j += 256)
        x[j] = we[(size_t)id * HH + j] + pe[(size_t)s * HH + j] + te[j];
    __syncthreads();

    float sum = x[tid] + x[tid + 256] + x[tid + 512];
    red[tid] = sum; __syncthreads();
    for (int s2 = 128; s2 > 0; s2 >>= 1) { if (tid < s2) red[tid] += red[tid + s2]; __syncthreads(); }
    const float mean = red[0] * (1.0f / HH);
    __syncthreads();

    const float c0 = x[tid] - mean, c1 = x[tid + 256] - mean, c2 = x[tid + 512] - mean;
    red[tid] = c0 * c0 + c1 * c1 + c2 * c2; __syncthreads();
    for (int s2 = 128; s2 > 0; s2 >>= 1) { if (tid < s2) red[tid] += red[tid + s2]; __syncthreads(); }
    const float inv = rsqrtf(red[0] * (1.0f / HH) + LN_EPS);

    h[(size_t)t * HH + tid      ] = __float2bfloat16(c0 * inv * g[tid      ] + b[tid      ]);
    h[(size_t)t * HH + tid + 256] = __float2bfloat16(c1 * inv * g[tid + 256] + b[tid + 256]);
    h[(size_t)t * HH + tid + 512] = __float2bfloat16(c2 * inv * g[tid + 512] + b[tid + 512]);
}

// ---------------------------------------------------------------------------
// Residual(bf16) + sum of P fp32 partials (+bias) -> LayerNorm -> bf16
// (in-place safe per-row)
// ---------------------------------------------------------------------------
__global__ __launch_bounds__(256) void add_ln(
    const __hip_bfloat16* __restrict__ resid, const float* __restrict__ y,
    int P, const float* __restrict__ bias,
    const float* __restrict__ g, const float* __restrict__ b,
    __hip_bfloat16* __restrict__ hout)
{
    const int t = blockIdx.x;
    const int tid = threadIdx.x;
    __shared__ float x[HH];
    __shared__ float red[256];

    for (int j = tid; j < HH; j += 256) {
        float s = __bfloat162float(resid[(size_t)t * HH + j]);
        if (bias) s += bias[j];
        for (int p = 0; p < P; ++p)
            s += y[(size_t)p * TT * HH + (size_t)t * HH + j];
        x[j] = s;
    }
    __syncthreads();

    float sum = x[tid] + x[tid + 256] + x[tid + 512];
    red[tid] = sum; __syncthreads();
    for (int s2 = 128; s2 > 0; s2 >>= 1) { if (tid < s2) red[tid] += red[tid + s2]; __syncthreads(); }
    const float mean = red[0] * (1.0f / HH);
    __syncthreads();

    const float c0 = x[tid] - mean, c1 = x[tid + 256] - mean, c2 = x[tid + 512] - mean;
    red[tid] = c0 * c0 + c1 * c1 + c2 * c2; __syncthreads();
    for (int s2 = 128; s2 > 0; s2 >>= 1) { if (tid < s2) red[tid] += red[tid + s2]; __syncthreads(); }
    const float inv = rsqrtf(red[0] * (1.0f / HH) + LN_EPS);

    hout[(size_t)t * HH + tid      ] = __float2bfloat16(c0 * inv * g[tid      ] + b[tid      ]);
    hout[(size_t)t * HH + tid + 256] = __float2bfloat16(c1 * inv * g[tid + 256] + b[tid + 256]);
    hout[(size_t)t * HH + tid + 512] = __float2bfloat16(c2 * inv * g[tid + 512] + b[tid + 512]);
}

// ---------------------------------------------------------------------------
// MFMA flash attention.
// Block = 256 threads = 4 waves; each wave owns 32 queries (q0 = qb + wid*32).
// Per 64-key tile:
//   - K staged row-major bf16 in LDS [64][64], XOR-swizzled (byte ^= (key&7)<<4)
//   - V staged TRANSPOSED bf16 in LDS Vt[d][key], XOR-swizzled (byte ^= (d&7)<<4)
//   - S^T = mfma_32x32x16(K, Q): D[key][q], col = lane&31 = own q (swapped trick:
//     softmax reduction is in-lane + one shfl_xor(32))
//   - P^T -> bf16 B-fragments via pack2 + 4 shfl_xor(32) per k-slice
//   - O^T = mfma_32x32x16(Vt, P^T): D[dim][q], col = own q -> corr rescale in-lane
// Frag conventions (gfx950, verified D-layout m74/m101; A/B by the GEMM pattern):
//   A: lane holds A[l&31][(l>>5)*8 + j]   B: lane holds B[(l>>5)*8 + j][l&31]
//   D: col = l&31, row = (r&3) + 8*(r>>2) + 4*(l>>5)
// ---------------------------------------------------------------------------
__global__ __launch_bounds__(256) void attn_mfma(
    const float* __restrict__ qkv, __hip_bfloat16* __restrict__ ctx)
{
    const int qb  = blockIdx.x * 128;
    const int hh  = blockIdx.y;
    const int b   = blockIdx.z;
    const int tid = threadIdx.x;
    const int wid = tid >> 6;
    const int lane = tid & 63;
    const int lq = lane & 31;     // this lane's query column
    const int w  = lane >> 5;     // half-select

    __shared__ __hip_bfloat16 Kb[64 * 64];   // [key][d] swizzled, 8 KB
    __shared__ __hip_bfloat16 Vt[64 * 64];   // [d][key] swizzled, 8 KB

    const int q0 = qb + wid * 32;
    const int i  = q0 + lq;

    // ---- Q fragments, pre-scaled by 1/8: qf[kt][j] = Q[i][kt*16 + w*8 + j]
    short8 qf[4];
    {
        const float* qrow = qkv + (size_t)(b * SS + i) * QKVN + hh * DHH;
        #pragma unroll
        for (int kt = 0; kt < 4; ++kt) {
            const float4 x0 = *(const float4*)(qrow + kt * 16 + w * 8);
            const float4 x1 = *(const float4*)(qrow + kt * 16 + w * 8 + 4);
            short8 q8;
            q8[0] = f2bs(x0.x * 0.125f); q8[1] = f2bs(x0.y * 0.125f);
            q8[2] = f2bs(x0.z * 0.125f); q8[3] = f2bs(x0.w * 0.125f);
            q8[4] = f2bs(x1.x * 0.125f); q8[5] = f2bs(x1.y * 0.125f);
            q8[6] = f2bs(x1.z * 0.125f); q8[7] = f2bs(x1.w * 0.125f);
            qf[kt] = q8;
        }
    }

    floatx16 acc_o[2] = {};          // O^T accum: row = dim (mtd*32 + rm), col = own q
    float m_run = -1e30f, l_run = 0.f;

    // staging index maps (all 256 threads)
    const int skey = tid >> 2;           // K: key row 0..63
    const int sd4  = (tid & 3) << 2;     // K: dim base {0,4,8,12}, +16x per step
    const int vd   = tid & 63;           // V: dim (row of Vt)
    const int vk0  = (tid >> 6) << 4;    // V: key base {0,16,32,48}

    const int kmax = (qb + 128 > PROMPT) ? (qb + 128) : PROMPT;

    for (int j0 = 0; j0 < kmax; j0 += 64) {
        // ---- stage K tile: coalesced dwordx4 loads, swizzled b64 LDS writes
        {
            const float* kg = qkv + (size_t)(b * SS + j0 + skey) * QKVN + HH + hh * DHH;
            char* krow = (char*)Kb + skey * 128;
            const int sw = (skey & 7) << 4;
            #pragma unroll
            for (int x = 0; x < 4; ++x) {
                const float4 f = *(const float4*)(kg + sd4 + 16 * x);
                short4v kv;
                kv[0] = f2bs(f.x); kv[1] = f2bs(f.y); kv[2] = f2bs(f.z); kv[3] = f2bs(f.w);
                *(short4v*)(krow + (((sd4 << 1) + (x << 5)) ^ sw)) = kv;
            }
        }
        // ---- stage V tile transposed: coalesced scalar loads (lane = dim),
        //      contiguous swizzled b128 LDS writes along keys
        {
            const float* vg = qkv + (size_t)(b * SS + j0 + vk0) * QKVN + 2 * HH + hh * DHH + vd;
            char* vrow = (char*)Vt + vd * 128;
            const int sw = (vd & 7) << 4;
            short8 v8a, v8b;
            #pragma unroll
            for (int x = 0; x < 8; ++x) v8a[x] = f2bs(vg[(size_t)x * QKVN]);
            #pragma unroll
            for (int x = 0; x < 8; ++x) v8b[x] = f2bs(vg[(size_t)(x + 8) * QKVN]);
            *(short8*)(vrow + ((vk0 << 1) ^ sw))        = v8a;
            *(short8*)(vrow + (((vk0 << 1) + 16) ^ sw)) = v8b;
        }
        __syncthreads();

        // ---- S^T = K x Q^T : s_acc[mt] covers keys mt*32..+31 for own q
        floatx16 s_acc[2];
        #pragma unroll
        for (int mt = 0; mt < 2; ++mt) {
            const char* krow = (const char*)Kb + (mt * 32 + lq) * 128;
            const int sw = (lq & 7) << 4;
            floatx16 acc = {};
            #pragma unroll
            for (int kt = 0; kt < 4; ++kt) {
                const short8 kf = *(const short8*)(krow + ((kt * 32 + w * 16) ^ sw));
                acc = __builtin_amdgcn_mfma_f32_32x32x16_bf16(kf, qf[kt], acc, 0, 0, 0);
            }
            s_acc[mt] = acc;
        }

        // ---- prefix-LM mask (element key index: j0 + mt*32 + (r&3) + 8*(r>>2) + 4w)
        const bool tfull = ((j0 + 63) < PROMPT) || ((j0 + 63) <= q0);
        if (!tfull) {
            #pragma unroll
            for (int mt = 0; mt < 2; ++mt)
                #pragma unroll
                for (int r = 0; r < 16; ++r) {
                    const int key = j0 + mt * 32 + (r & 3) + ((r >> 2) << 3) + (w << 2);
                    if (key >= PROMPT && key > i) s_acc[mt][r] = -1e30f;
                }
        }

        // ---- online softmax (own 32 values + partner half via shfl_xor(32))
        float tmax = -1e30f;
        #pragma unroll
        for (int mt = 0; mt < 2; ++mt)
            #pragma unroll
            for (int r = 0; r < 16; ++r) tmax = fmaxf(tmax, s_acc[mt][r]);
        tmax = fmaxf(tmax, __shfl_xor(tmax, 32, 64));
        const float mnew = fmaxf(m_run, tmax);
        const float corr = __expf(m_run - mnew);
        m_run = mnew;
        float psum = 0.f;
        #pragma unroll
        for (int mt = 0; mt < 2; ++mt)
            #pragma unroll
            for (int r = 0; r < 16; ++r) {
                const float p = __expf(s_acc[mt][r] - mnew);
                s_acc[mt][r] = p;
                psum += p;
            }
        l_run = l_run * corr + psum;    // per-half-lane sum; combined at end
        #pragma unroll
        for (int r = 0; r < 16; ++r) { acc_o[0][r] *= corr; acc_o[1][r] *= corr; }

        // ---- P^T -> bf16 B-fragments: pbf[kt][j] = P[key = kt*16 + w*8 + j][own q]
        short8 pbf[4];
        #pragma unroll
        for (int kt = 0; kt < 4; ++kt) {
            const int mt = kt >> 1;
            const int c0 = ((2 * kt) & 3) << 2;
            const int c1 = ((2 * kt + 1) & 3) << 2;
            const int w0 = pack2(s_acc[mt][c0 + 0], s_acc[mt][c0 + 1]);
            const int w1 = pack2(s_acc[mt][c0 + 2], s_acc[mt][c0 + 3]);
            const int w2 = pack2(s_acc[mt][c1 + 0], s_acc[mt][c1 + 1]);
            const int w3 = pack2(s_acc[mt][c1 + 2], s_acc[mt][c1 + 3]);
            const int t0 = __shfl_xor(w0, 32, 64);
            const int t1 = __shfl_xor(w1, 32, 64);
            const int t2 = __shfl_xor(w2, 32, 64);
            const int t3 = __shfl_xor(w3, 32, 64);
            I4S8 u;
            u.i[0] = w ? t2 : w0;
            u.i[1] = w ? t3 : w1;
            u.i[2] = w ? w2 : t0;
            u.i[3] = w ? w3 : t1;
            pbf[kt] = u.s;
        }

        // ---- O^T += Vt x P^T
        #pragma unroll
        for (int mtd = 0; mtd < 2; ++mtd) {
            const char* vrow = (const char*)Vt + (mtd * 32 + lq) * 128;
            const int sw = (lq & 7) << 4;
            #pragma unroll
            for (int kt = 0; kt < 4; ++kt) {
                const short8 vf = *(const short8*)(vrow + ((kt * 32 + w * 16) ^ sw));
                acc_o[mtd] = __builtin_amdgcn_mfma_f32_32x32x16_bf16(vf, pbf[kt], acc_o[mtd], 0, 0, 0);
            }
        }
        __syncthreads();
    }

    // ---- epilogue: combine halves, normalize, store (dims 4-contiguous per chunk)
    const float lt  = l_run + __shfl_xor(l_run, 32, 64);
    const float inv = 1.0f / lt;
    __hip_bfloat16* crow = ctx + (size_t)(b * SS + i) * HH + hh * DHH;
    #pragma unroll
    for (int mtd = 0; mtd < 2; ++mtd)
        #pragma unroll
        for (int rq = 0; rq < 4; ++rq) {
            short4v o4;
            #pragma unroll
            for (int e = 0; e < 4; ++e)
                o4[e] = f2bs(acc_o[mtd][rq * 4 + e] * inv);
            *(short4v*)(crow + mtd * 32 + rq * 8 + w * 4) = o4;
        }
}

// ---------------------------------------------------------------------------
// CE over one batch-chunk of logits (384 rows)
// ---------------------------------------------------------------------------
__global__ __launch_bounds__(256) void ce_kernel(
    const float* __restrict__ logits, const int* __restrict__ labels,
    int bidx, float* __restrict__ acc)
{
    const int r = blockIdx.x;
    const int t = bidx * SS + PROMPT + r;
    const float* row = logits + (size_t)r * VV;
    const int tid = threadIdx.x;
    __shared__ float red[256];

    float mx = -1e30f;
    for (int c = tid; c < VV; c += 256) mx = fmaxf(mx, row[c]);
    red[tid] = mx; __syncthreads();
    for (int s2 = 128; s2 > 0; s2 >>= 1) { if (tid < s2) red[tid] = fmaxf(red[tid], red[tid + s2]); __syncthreads(); }
    mx = red[0];
    __syncthreads();

    float se = 0.f;
    for (int c = tid; c < VV; c += 256) se += __expf(row[c] - mx);
    red[tid] = se; __syncthreads();
    for (int s2 = 128; s2 > 0; s2 >>= 1) { if (tid < s2) red[tid] += red[tid + s2]; __syncthreads(); }

    if (tid == 0) {
        const int lab = labels[t];
        if (lab >= 0) {
            const float nll = -(row[lab] - mx - logf(red[0]));
            atomicAdd(&acc[0], nll);
            atomicAdd(&acc[1], 1.0f);
        }
    }
}

__global__ void finalize_kernel(const float* __restrict__ acc, float* __restrict__ out)
{
    out[0] = (acc[1] > 0.f) ? acc[0] / acc[1] : 0.f;
}

// ---------------------------------------------------------------------------
extern "C" void kernel_launch(void* const* d_in, const int* in_sizes, int n_in,
                              void* d_out, int out_size, void* d_ws, size_t ws_size,
                              hipStream_t stream)
{
    const int*   input_ids = (const int*)  d_in[0];
    const int*   labels    = (const int*)  d_in[1];
    const float* word_emb  = (const float*)d_in[2];
    const float* pos_emb   = (const float*)d_in[3];
    const float* type_emb  = (const float*)d_in[4];
    const float* emb_ln_g  = (const float*)d_in[5];
    const float* emb_ln_b  = (const float*)d_in[6];
    const float* Wq = (const float*)d_in[7];   const float* bq = (const float*)d_in[8];
    const float* Wk = (const float*)d_in[9];   const float* bk = (const float*)d_in[10];
    const float* Wv = (const float*)d_in[11];  const float* bv = (const float*)d_in[12];
    const float* Wo = (const float*)d_in[13];  const float* bo = (const float*)d_in[14];
    const float* ln1_g = (const float*)d_in[15]; const float* ln1_b = (const float*)d_in[16];
    const float* W1 = (const float*)d_in[17];  const float* bf1 = (const float*)d_in[18];
    const float* W2 = (const float*)d_in[19];  const float* bf2 = (const float*)d_in[20];
    const float* ln2_g = (const float*)d_in[21]; const float* ln2_b = (const float*)d_in[22];
    const float* Wc = (const float*)d_in[23];  const float* bc = (const float*)d_in[24];

    // ---- workspace layout (fp32 first, then bf16) ----
    float* fws = (float*)d_ws;
    float* qkv  = fws;                        // 4096*2304 = 9,437,184 f
    float* lg   = qkv;                        // alias: 384*21128 = 8,113,152 f < qkv size
    float* part = qkv;                        // alias: split-K partials, <= 3*4096*768 f
    float* tmp  = qkv + (size_t)TT * QKVN;    // 4096*768 (unused, kept for layout)
    float* bqkv = tmp + (size_t)TT * HH;      // 12*2304
    float* acc  = bqkv + (size_t)LL * QKVN;   // 2 (+pad)

    __hip_bfloat16* bws = (__hip_bfloat16*)(acc + 8);
    __hip_bfloat16* h    = bws;                                   // 4096*768
    __hip_bfloat16* ctx  = h    + (size_t)TT * HH;                // 4096*768
    __hip_bfloat16* ff1  = ctx  + (size_t)TT * HH;                // 4096*3072
    __hip_bfloat16* qkvw = ff1  + (size_t)TT * FFF;               // 12*2304*768
    __hip_bfloat16* wot  = qkvw + (size_t)LL * QKVN * HH;         // 12*768*768
    __hip_bfloat16* w1t  = wot  + (size_t)LL * HH * HH;           // 12*3072*768
    __hip_bfloat16* w2t  = w1t  + (size_t)LL * FFF * HH;          // 12*768*3072
    __hip_bfloat16* wct  = w2t  + (size_t)LL * HH * FFF;          // 21248*768

    hipMemsetAsync(acc, 0, 2 * sizeof(float), stream);

    // ---- weight convert + transpose (bf16, K-contiguous) ----
    const dim3 tb(32, 8);
    transpose_cvt<<<dim3(24, 24, LL), tb, 0, stream>>>(Wq, qkvw, HH, HH,
        (long long)HH * HH, (long long)QKVN * HH, 0, HH);
    transpose_cvt<<<dim3(24, 24, LL), tb, 0, stream>>>(Wk, qkvw, HH, HH,
        (long long)HH * HH, (long long)QKVN * HH, HH, HH);
    transpose_cvt<<<dim3(24, 24, LL), tb, 0, stream>>>(Wv, qkvw, HH, HH,
        (long long)HH * HH, (long long)QKVN * HH, 2 * HH, HH);
    transpose_cvt<<<dim3(24, 24, LL), tb, 0, stream>>>(Wo, wot, HH, HH,
        (long long)HH * HH, (long long)HH * HH, 0, HH);
    transpose_cvt<<<dim3(96, 24, LL), tb, 0, stream>>>(W1, w1t, HH, FFF,
        (long long)HH * FFF, (long long)FFF * HH, 0, HH);
    transpose_cvt<<<dim3(24, 96, LL), tb, 0, stream>>>(W2, w2t, FFF, HH,
        (long long)FFF * HH, (long long)HH * FFF, 0, FFF);
    transpose_cvt<<<dim3(661, 24, 1), tb, 0, stream>>>(Wc, wct, HH, VV,
        0, 0, 0, HH);
    concat_bias<<<(LL * QKVN + 255) / 256, 256, 0, stream>>>(bq, bk, bv, bqkv);

    // ---- embeddings ----
    embed_ln<<<TT, 256, 0, stream>>>(input_ids, word_emb, pos_emb, type_emb,
                                     emb_ln_g, emb_ln_b, h);

    const dim3 gQKV(QKVN / 128, TT / 128, 1);   // 18 x 32
    const dim3 gWo (HH / 128,  TT / 128, 2);    // 6 x 32 x 2  (split-K=2, Kc=384)
    const dim3 gF  (FFF / 128, TT / 128, 1);    // 24 x 32
    const dim3 gFF2(HH / 128,  TT / 128, 3);    // 6 x 32 x 3  (split-K=3, Kc=1024)
    const dim3 gAttn(SS / 128, NHH, BB);        // 4 x 12 x 8

    for (int l = 0; l < LL; ++l) {
        gemm_mfma<<<gQKV, 256, 0, stream>>>(h, qkvw + (size_t)l * QKVN * HH,
            bqkv + (size_t)l * QKVN, qkv, nullptr, TT, QKVN, HH, 0);

        attn_mfma<<<gAttn, 256, 0, stream>>>(qkv, ctx);

        // ctx @ Wo^T -> 2 fp32 partials (qkv buffer is dead now)
        gemm_mfma<<<gWo, 256, 0, stream>>>(ctx, wot + (size_t)l * HH * HH,
            nullptr, part, nullptr, TT, HH, HH, 0);
        add_ln<<<TT, 256, 0, stream>>>(h, part, 2, bo + (size_t)l * HH,
            ln1_g + (size_t)l * HH, ln1_b + (size_t)l * HH, h);

        gemm_mfma<<<gF, 256, 0, stream>>>(h, w1t + (size_t)l * FFF * HH,
            bf1 + (size_t)l * FFF, nullptr, ff1, TT, FFF, HH, 1);

        // ff1 @ W2^T -> 3 fp32 partials
        gemm_mfma<<<gFF2, 256, 0, stream>>>(ff1, w2t + (size_t)l * HH * FFF,
            nullptr, part, nullptr, TT, HH, FFF, 0);
        add_ln<<<TT, 256, 0, stream>>>(h, part, 3, bf2 + (size_t)l * HH,
            ln2_g + (size_t)l * HH, ln2_b + (size_t)l * HH, h);
    }

    // ---- LM head + CE per batch (only s >= PROMPT rows) ----
    const int Mchunk = SS - PROMPT;              // 384
    const dim3 gV(VVP / 128, Mchunk / 128, 1);   // 166 x 3
    for (int b = 0; b < BB; ++b) {
        const __hip_bfloat16* Arow = h + (size_t)(b * SS + PROMPT) * HH;
        gemm_mfma<<<gV, 256, 0, stream>>>(Arow, wct, bc, lg, nullptr, Mchunk, VV, HH, 0);
        ce_kernel<<<Mchunk, 256, 0, stream>>>(lg, labels, b, acc);
    }

    finalize_kernel<<<1, 1, 0, stream>>>(acc, (float*)d_out);
}

// Round 4
// 3922.959 us; speedup vs baseline: 2.0593x; 1.1272x over previous
//
#include <hip/hip_runtime.h>
#include <hip/hip_bf16.h>
#include <math.h>

// Problem constants
#define BB 8
#define SS 512
#define HH 768
#define NHH 12
#define DHH 64
#define LL 12
#define VV 21128
#define VVP 21248          // VV padded up to multiple of 128
#define FFF 3072
#define TT (BB*SS)         // 4096 tokens
#define PROMPT 128
#define LN_EPS 1e-12f
#define QKVN (3*HH)        // 2304

typedef __attribute__((ext_vector_type(8))) short short8;
typedef __attribute__((ext_vector_type(4))) short short4v;
typedef __attribute__((ext_vector_type(4))) float floatx4;
typedef __attribute__((ext_vector_type(16))) float floatx16;

__device__ __forceinline__ float gelu_exact(float x) {
    return 0.5f * x * (1.0f + erff(x * 0.70710678118654752f));
}

__device__ __forceinline__ short f2bs(float x) {
    __hip_bfloat16 h = __float2bfloat16(x);
    return *reinterpret_cast<short*>(&h);
}

__device__ __forceinline__ int pack2(float a, float b) {
    const unsigned int lo = (unsigned short)f2bs(a);
    const unsigned int hi = (unsigned short)f2bs(b);
    return (int)(lo | (hi << 16));
}

union I4S8 { int i[4]; short8 s; };

// async global->LDS, 16B per lane; ldsptr must be wave-uniform + lane*16
__device__ __forceinline__ void load16_lds(const void* gptr, void* ldsptr) {
    __builtin_amdgcn_global_load_lds(
        (const __attribute__((address_space(1))) unsigned int*)(unsigned long long)(gptr),
        (__attribute__((address_space(3))) unsigned int*)(unsigned long long)(ldsptr),
        16, 0, 0);
}

// ---------------------------------------------------------------------------
// bf16 MFMA GEMM: C[M,N] = A[M,K] @ Bt[N,K]^T (+bias) (+gelu)
// A row-major [M,K] bf16, Bt row-major [Npad,K] bf16. 128x128 tile, BK=64,
// 256 threads = 4 waves (2x2 of 64x64), 4x4 MFMA frags per wave.
// DOUBLE-BUFFERED LDS (2x 16KB per operand, 64 KB total), ONE barrier/iter:
//   prologue: STAGE(buf0, k=0); barrier
//   iter t:   STAGE(buf^1, k(t+1)); ds_read+MFMA from buf; vmcnt0+barrier
// so global->LDS latency of tile t+1 hides under tile t's 32 MFMAs.
// Chunk XOR-swizzle as before: logical 16B chunk (row,c) at slot (row, c^(row&7));
// LDS dest stays linear (global_load_lds), GLOBAL source is pre-swizzled.
// Split-K: gridDim.z = P chunks; each writes fp32 partial Cf + z*M*N.
// M % 128 == 0, K % (64*P) == 0. N ragged allowed (epilogue guard).
// ---------------------------------------------------------------------------
__global__ __launch_bounds__(256) void gemm_mfma(
    const __hip_bfloat16* __restrict__ A,
    const __hip_bfloat16* __restrict__ Bt,
    const float* __restrict__ bias,
    float* __restrict__ Cf,            // fp32 out (or null)
    __hip_bfloat16* __restrict__ Ch,   // bf16 out (or null)
    int M, int N, int K, int act)
{
    __shared__ __hip_bfloat16 As[2][128 * 64];   // 32 KB
    __shared__ __hip_bfloat16 Bs[2][128 * 64];   // 32 KB

    const int tid  = threadIdx.x;
    const int wid  = tid >> 6;
    const int lane = tid & 63;
    const int row0 = blockIdx.y * 128;
    const int col0 = blockIdx.x * 128;

    const int wm = wid >> 1, wn = wid & 1;
    const int lr = lane >> 4, lc = lane & 15;

    // split-K
    const int nz   = gridDim.z;
    const int Kc   = K / nz;
    const int kbeg = blockIdx.z * Kc;
    if (nz > 1) Cf += (size_t)blockIdx.z * M * N;

    floatx4 acc[4][4] = {};

    // staging map: 16B chunks. pass p covers rows p*32..p*32+31.
    // row = p*32 + (tid>>3), logical chunk c = tid&7, source chunk = c ^ (row&7).
    const int sRow = tid >> 3;                  // 0..31 (+32 per p)
    const int sC   = (tid & 7) ^ (sRow & 7);    // pre-swizzled source chunk
    const __hip_bfloat16* aG[4];
    const __hip_bfloat16* bG[4];
    #pragma unroll
    for (int p = 0; p < 4; ++p) {
        aG[p] = A  + (size_t)(row0 + p * 32 + sRow) * K + kbeg + sC * 8;
        bG[p] = Bt + (size_t)(col0 + p * 32 + sRow) * K + kbeg + sC * 8;
    }

    const int nIter = Kc >> 6;

#define STAGE(buf, k0elem) do {                                      \
        char* aD = (char*)As + (buf) * 16384 + wid * 1024;           \
        char* bD = (char*)Bs + (buf) * 16384 + wid * 1024;           \
        _Pragma("unroll")                                            \
        for (int p = 0; p < 4; ++p) {                                \
            load16_lds(aG[p] + (k0elem), aD + p * 4096);             \
            load16_lds(bG[p] + (k0elem), bD + p * 4096);             \
        }                                                            \
    } while (0)

    STAGE(0, 0);
    __syncthreads();            // drains vmcnt(0): tile 0 ready

    int cur = 0;
    for (int t = 0; t < nIter; ++t) {
        if (t + 1 < nIter) STAGE(cur ^ 1, (t + 1) << 6);   // prefetch next tile

        const char* Ab = (const char*)As + cur * 16384;
        const char* Bb = (const char*)Bs + cur * 16384;

        __builtin_amdgcn_s_setprio(1);
        #pragma unroll
        for (int ks = 0; ks < 2; ++ks) {
            short8 af[4], bfr[4];
            #pragma unroll
            for (int mt = 0; mt < 4; ++mt) {
                const int row = wm * 64 + mt * 16 + lc;
                af[mt] = *(const short8*)(Ab + row * 128 +
                         ((((ks << 2) | lr) ^ (row & 7)) << 4));
            }
            #pragma unroll
            for (int nt = 0; nt < 4; ++nt) {
                const int row = wn * 64 + nt * 16 + lc;
                bfr[nt] = *(const short8*)(Bb + row * 128 +
                          ((((ks << 2) | lr) ^ (row & 7)) << 4));
            }
            #pragma unroll
            for (int mt = 0; mt < 4; ++mt)
                #pragma unroll
                for (int nt = 0; nt < 4; ++nt)
                    acc[mt][nt] = __builtin_amdgcn_mfma_f32_16x16x32_bf16(
                        af[mt], bfr[nt], acc[mt][nt], 0, 0, 0);
        }
        __builtin_amdgcn_s_setprio(0);

        __syncthreads();        // drains vmcnt(0) (prefetch done) + all reads done
        cur ^= 1;
    }
#undef STAGE

    #pragma unroll
    for (int mt = 0; mt < 4; ++mt) {
        #pragma unroll
        for (int nt = 0; nt < 4; ++nt) {
            const int n = col0 + wn * 64 + nt * 16 + lc;
            if (n < N) {
                #pragma unroll
                for (int r = 0; r < 4; ++r) {
                    const int m = row0 + wm * 64 + mt * 16 + lr * 4 + r;
                    float v = acc[mt][nt][r];
                    if (bias) v += bias[n];
                    if (act)  v = gelu_exact(v);
                    if (Cf) Cf[(size_t)m * N + n] = v;
                    if (Ch) Ch[(size_t)m * N + n] = __float2bfloat16(v);
                }
            }
        }
    }
}

// ---------------------------------------------------------------------------
// fp32 -> bf16 transpose: out[z][row_off + n][k] = (bf16) W[z][k][n]
// ---------------------------------------------------------------------------
__global__ void transpose_cvt(
    const float* __restrict__ W, __hip_bfloat16* __restrict__ out,
    int K, int N, long long in_lstride, long long out_lstride,
    int row_off, int out_ld)
{
    __shared__ float t[32][33];
    const int n0 = blockIdx.x * 32;
    const int k0 = blockIdx.y * 32;
    const int z  = blockIdx.z;
    const int tx = threadIdx.x, ty = threadIdx.y;

    const float* Wz = W + (size_t)z * in_lstride;
    __hip_bfloat16* Oz = out + (size_t)z * out_lstride;

    #pragma unroll
    for (int r = 0; r < 4; ++r) {
        const int k = k0 + ty + r * 8;
        const int n = n0 + tx;
        if (k < K && n < N) t[ty + r * 8][tx] = Wz[(size_t)k * N + n];
    }
    __syncthreads();
    #pragma unroll
    for (int r = 0; r < 4; ++r) {
        const int n = n0 + ty + r * 8;
        const int k = k0 + tx;
        if (n < N && k < K)
            Oz[(size_t)(row_off + n) * out_ld + k] = __float2bfloat16(t[tx][ty + r * 8]);
    }
}

__global__ void concat_bias(const float* __restrict__ bq, const float* __restrict__ bk,
                            const float* __restrict__ bv, float* __restrict__ bqkv)
{
    const int i = blockIdx.x * 256 + threadIdx.x;
    if (i >= LL * QKVN) return;
    const int l = i / QKVN, j = i % QKVN;
    float v;
    if (j < HH)            v = bq[l * HH + j];
    else if (j < 2 * HH)   v = bk[l * HH + j - HH];
    else                   v = bv[l * HH + j - 2 * HH];
    bqkv[i] = v;
}

// ---------------------------------------------------------------------------
// Embedding + LayerNorm -> bf16 h
// ---------------------------------------------------------------------------
__global__ __launch_bounds__(256) void embed_ln(
    const int* __restrict__ ids, const float* __restrict__ we,
    const float* __restrict__ pe, const float* __restrict__ te,
    const float* __restrict__ g, const float* __restrict__ b,
    __hip_bfloat16* __restrict__ h)
{
    const int t = blockIdx.x;
    const int s = t & (SS - 1);
    const int tid = threadIdx.x;
    __shared__ float x[HH];
    __shared__ float red[256];

    const int id = ids[t];
    for (int j = tid; j < HH; j += 256)
        x[j] = we[(size_t)id * HH + j] + pe[(size_t)s * HH + j] + te[j];
    __syncthreads();

    float sum = x[tid] + x[tid + 256] + x[tid + 512];
    red[tid] = sum; __syncthreads();
    for (int s2 = 128; s2 > 0; s2 >>= 1) { if (tid < s2) red[tid] += red[tid + s2]; __syncthreads(); }
    const float mean = red[0] * (1.0f / HH);
    __syncthreads();

    const float c0 = x[tid] - mean, c1 = x[tid + 256] - mean, c2 = x[tid + 512] - mean;
    red[tid] = c0 * c0 + c1 * c1 + c2 * c2; __syncthreads();
    for (int s2 = 128; s2 > 0; s2 >>= 1) { if (tid < s2) red[tid] += red[tid + s2]; __syncthreads(); }
    const float inv = rsqrtf(red[0] * (1.0f / HH) + LN_EPS);

    h[(size_t)t * HH + tid      ] = __float2bfloat16(c0 * inv * g[tid      ] + b[tid      ]);
    h[(size_t)t * HH + tid + 256] = __float2bfloat16(c1 * inv * g[tid + 256] + b[tid + 256]);
    h[(size_t)t * HH + tid + 512] = __float2bfloat16(c2 * inv * g[tid + 512] + b[tid + 512]);
}

// ---------------------------------------------------------------------------
// Residual(bf16) + sum of P fp32 partials (+bias) -> LayerNorm -> bf16
// (in-place safe per-row)
// ---------------------------------------------------------------------------
__global__ __launch_bounds__(256) void add_ln(
    const __hip_bfloat16* __restrict__ resid, const float* __restrict__ y,
    int P, const float* __restrict__ bias,
    const float* __restrict__ g, const float* __restrict__ b,
    __hip_bfloat16* __restrict__ hout)
{
    const int t = blockIdx.x;
    const int tid = threadIdx.x;
    __shared__ float x[HH];
    __shared__ float red[256];

    for (int j = tid; j < HH; j += 256) {
        float s = __bfloat162float(resid[(size_t)t * HH + j]);
        if (bias) s += bias[j];
        for (int p = 0; p < P; ++p)
            s += y[(size_t)p * TT * HH + (size_t)t * HH + j];
        x[j] = s;
    }
    __syncthreads();

    float sum = x[tid] + x[tid + 256] + x[tid + 512];
    red[tid] = sum; __syncthreads();
    for (int s2 = 128; s2 > 0; s2 >>= 1) { if (tid < s2) red[tid] += red[tid + s2]; __syncthreads(); }
    const float mean = red[0] * (1.0f / HH);
    __syncthreads();

    const float c0 = x[tid] - mean, c1 = x[tid + 256] - mean, c2 = x[tid + 512] - mean;
    red[tid] = c0 * c0 + c1 * c1 + c2 * c2; __syncthreads();
    for (int s2 = 128; s2 > 0; s2 >>= 1) { if (tid < s2) red[tid] += red[tid + s2]; __syncthreads(); }
    const float inv = rsqrtf(red[0] * (1.0f / HH) + LN_EPS);

    hout[(size_t)t * HH + tid      ] = __float2bfloat16(c0 * inv * g[tid      ] + b[tid      ]);
    hout[(size_t)t * HH + tid + 256] = __float2bfloat16(c1 * inv * g[tid + 256] + b[tid + 256]);
    hout[(size_t)t * HH + tid + 512] = __float2bfloat16(c2 * inv * g[tid + 512] + b[tid + 512]);
}

// ---------------------------------------------------------------------------
// MFMA flash attention over bf16 qkv [T, 2304] (Q|K|V).
// Block = 256 threads = 4 waves; each wave owns 32 queries (q0 = qb + wid*32).
// Per 64-key tile:
//   - K staged via global_load_lds (linear LDS dest, pre-swizzled global
//     source chunk c^(row&7)); logical layout [key][64d] bf16, swizzled.
//   - V staged TRANSPOSED bf16 Vt[d][key], XOR-swizzled (byte ^= (d&7)<<4)
//   - S^T = mfma_32x32x16(K, Q): D[key][q], col = lane&31 = own q; scale by
//     1/8 applied to S post-MFMA (exact, so Q needs no pre-scaling)
//   - P^T -> bf16 B-fragments via pack2 + 4 shfl_xor(32) per k-slice
//   - O^T = mfma_32x32x16(Vt, P^T): D[dim][q], col = own q
// Frag conventions (gfx950):
//   A: lane holds A[l&31][(l>>5)*8 + j]   B: lane holds B[(l>>5)*8 + j][l&31]
//   D: col = l&31, row = (r&3) + 8*(r>>2) + 4*(l>>5)
// ---------------------------------------------------------------------------
__global__ __launch_bounds__(256) void attn_mfma(
    const __hip_bfloat16* __restrict__ qkv, __hip_bfloat16* __restrict__ ctx)
{
    const int qb  = blockIdx.x * 128;
    const int hh  = blockIdx.y;
    const int b   = blockIdx.z;
    const int tid = threadIdx.x;
    const int wid = tid >> 6;
    const int lane = tid & 63;
    const int lq = lane & 31;     // this lane's query column
    const int w  = lane >> 5;     // half-select

    __shared__ __hip_bfloat16 Kb[64 * 64];   // [key][d] swizzled, 8 KB
    __shared__ __hip_bfloat16 Vt[64 * 64];   // [d][key] swizzled, 8 KB

    const int q0 = qb + wid * 32;
    const int i  = q0 + lq;

    // ---- Q fragments (bf16, unscaled): qf[kt][j] = Q[i][kt*16 + w*8 + j]
    short8 qf[4];
    {
        const __hip_bfloat16* qrow = qkv + (size_t)(b * SS + i) * QKVN + hh * DHH;
        #pragma unroll
        for (int kt = 0; kt < 4; ++kt)
            qf[kt] = *(const short8*)(qrow + kt * 16 + w * 8);
    }

    floatx16 acc_o[2] = {};          // O^T accum: row = dim, col = own q
    float m_run = -1e30f, l_run = 0.f;

    // staging index maps (all 256 threads)
    const int kRow = tid >> 3;           // K: row within 32-row pass
    const int kC   = tid & 7;            // K: logical 16B chunk
    const int vd   = tid & 63;           // V: dim (row of Vt)
    const int vk0  = (tid >> 6) << 4;    // V: key base {0,16,32,48}

    const int kmax = (qb + 128 > PROMPT) ? (qb + 128) : PROMPT;

    for (int j0 = 0; j0 < kmax; j0 += 64) {
        // ---- stage K tile: async global->LDS, source chunk pre-swizzled
        #pragma unroll
        for (int x = 0; x < 2; ++x) {
            const int row = x * 32 + kRow;
            const __hip_bfloat16* src = qkv + (size_t)(b * SS + j0 + row) * QKVN
                                        + HH + hh * DHH + ((kC ^ (row & 7)) << 3);
            load16_lds(src, (char*)Kb + x * 4096 + wid * 1024 + (lane << 4));
        }
        // ---- stage V tile transposed: scalar bf16 loads (lane = dim),
        //      contiguous swizzled b128 LDS writes along keys
        {
            const short* vg = (const short*)(qkv + (size_t)(b * SS + j0 + vk0) * QKVN
                                             + 2 * HH + hh * DHH + vd);
            char* vrow = (char*)Vt + vd * 128;
            const int sw = (vd & 7) << 4;
            short8 v8a, v8b;
            #pragma unroll
            for (int x = 0; x < 8; ++x) v8a[x] = vg[(size_t)x * QKVN];
            #pragma unroll
            for (int x = 0; x < 8; ++x) v8b[x] = vg[(size_t)(x + 8) * QKVN];
            *(short8*)(vrow + ((vk0 << 1) ^ sw))        = v8a;
            *(short8*)(vrow + (((vk0 << 1) + 16) ^ sw)) = v8b;
        }
        __syncthreads();

        // ---- S^T = K x Q^T : s_acc[mt] covers keys mt*32..+31 for own q
        floatx16 s_acc[2];
        #pragma unroll
        for (int mt = 0; mt < 2; ++mt) {
            const char* krow = (const char*)Kb + (mt * 32 + lq) * 128;
            const int sw = (lq & 7) << 4;
            floatx16 acc = {};
            #pragma unroll
            for (int kt = 0; kt < 4; ++kt) {
                const short8 kf = *(const short8*)(krow + ((kt * 32 + w * 16) ^ sw));
                acc = __builtin_amdgcn_mfma_f32_32x32x16_bf16(kf, qf[kt], acc, 0, 0, 0);
            }
            s_acc[mt] = acc;
        }
        // ---- apply 1/sqrt(DH) = 1/8 scale
        #pragma unroll
        for (int mt = 0; mt < 2; ++mt)
            #pragma unroll
            for (int r = 0; r < 16; ++r) s_acc[mt][r] *= 0.125f;

        // ---- prefix-LM mask (element key index: j0 + mt*32 + (r&3) + 8*(r>>2) + 4w)
        const bool tfull = ((j0 + 63) < PROMPT) || ((j0 + 63) <= q0);
        if (!tfull) {
            #pragma unroll
            for (int mt = 0; mt < 2; ++mt)
                #pragma unroll
                for (int r = 0; r < 16; ++r) {
                    const int key = j0 + mt * 32 + (r & 3) + ((r >> 2) << 3) + (w << 2);
                    if (key >= PROMPT && key > i) s_acc[mt][r] = -1e30f;
                }
        }

        // ---- online softmax (own 32 values + partner half via shfl_xor(32))
        float tmax = -1e30f;
        #pragma unroll
        for (int mt = 0; mt < 2; ++mt)
            #pragma unroll
            for (int r = 0; r < 16; ++r) tmax = fmaxf(tmax, s_acc[mt][r]);
        tmax = fmaxf(tmax, __shfl_xor(tmax, 32, 64));
        const float mnew = fmaxf(m_run, tmax);
        const float corr = __expf(m_run - mnew);
        m_run = mnew;
        float psum = 0.f;
        #pragma unroll
        for (int mt = 0; mt < 2; ++mt)
            #pragma unroll
            for (int r = 0; r < 16; ++r) {
                const float p = __expf(s_acc[mt][r] - mnew);
                s_acc[mt][r] = p;
                psum += p;
            }
        l_run = l_run * corr + psum;    // per-half-lane sum; combined at end
        #pragma unroll
        for (int r = 0; r < 16; ++r) { acc_o[0][r] *= corr; acc_o[1][r] *= corr; }

        // ---- P^T -> bf16 B-fragments: pbf[kt][j] = P[key = kt*16 + w*8 + j][own q]
        short8 pbf[4];
        #pragma unroll
        for (int kt = 0; kt < 4; ++kt) {
            const int mt = kt >> 1;
            const int c0 = ((2 * kt) & 3) << 2;
            const int c1 = ((2 * kt + 1) & 3) << 2;
            const int w0 = pack2(s_acc[mt][c0 + 0], s_acc[mt][c0 + 1]);
            const int w1 = pack2(s_acc[mt][c0 + 2], s_acc[mt][c0 + 3]);
            const int w2 = pack2(s_acc[mt][c1 + 0], s_acc[mt][c1 + 1]);
            const int w3 = pack2(s_acc[mt][c1 + 2], s_acc[mt][c1 + 3]);
            const int t0 = __shfl_xor(w0, 32, 64);
            const int t1 = __shfl_xor(w1, 32, 64);
            const int t2 = __shfl_xor(w2, 32, 64);
            const int t3 = __shfl_xor(w3, 32, 64);
            I4S8 u;
            u.i[0] = w ? t2 : w0;
            u.i[1] = w ? t3 : w1;
            u.i[2] = w ? w2 : t0;
            u.i[3] = w ? w3 : t1;
            pbf[kt] = u.s;
        }

        // ---- O^T += Vt x P^T
        #pragma unroll
        for (int mtd = 0; mtd < 2; ++mtd) {
            const char* vrow = (const char*)Vt + (mtd * 32 + lq) * 128;
            const int sw = (lq & 7) << 4;
            #pragma unroll
            for (int kt = 0; kt < 4; ++kt) {
                const short8 vf = *(const short8*)(vrow + ((kt * 32 + w * 16) ^ sw));
                acc_o[mtd] = __builtin_amdgcn_mfma_f32_32x32x16_bf16(vf, pbf[kt], acc_o[mtd], 0, 0, 0);
            }
        }
        __syncthreads();
    }

    // ---- epilogue: combine halves, normalize, store (dims 4-contiguous per chunk)
    const float lt  = l_run + __shfl_xor(l_run, 32, 64);
    const float inv = 1.0f / lt;
    __hip_bfloat16* crow = ctx + (size_t)(b * SS + i) * HH + hh * DHH;
    #pragma unroll
    for (int mtd = 0; mtd < 2; ++mtd)
        #pragma unroll
        for (int rq = 0; rq < 4; ++rq) {
            short4v o4;
            #pragma unroll
            for (int e = 0; e < 4; ++e)
                o4[e] = f2bs(acc_o[mtd][rq * 4 + e] * inv);
            *(short4v*)(crow + mtd * 32 + rq * 8 + w * 4) = o4;
        }
}

// ---------------------------------------------------------------------------
// CE over one batch-chunk of logits (384 rows) — single-pass online softmax
// ---------------------------------------------------------------------------
__global__ __launch_bounds__(256) void ce_kernel(
    const float* __restrict__ logits, const int* __restrict__ labels,
    int bidx, float* __restrict__ acc)
{
    const int r = blockIdx.x;
    const int t = bidx * SS + PROMPT + r;
    const float* row = logits + (size_t)r * VV;
    const int tid = threadIdx.x;
    __shared__ float redm[256];
    __shared__ float reds[256];

    float mx = -1e30f, se = 0.f;
    for (int c4 = tid; c4 < VV / 4; c4 += 256) {
        const float4 v = ((const float4*)row)[c4];
        const float lm = fmaxf(fmaxf(v.x, v.y), fmaxf(v.z, v.w));
        if (lm > mx) { se *= __expf(mx - lm); mx = lm; }
        se += __expf(v.x - mx) + __expf(v.y - mx) + __expf(v.z - mx) + __expf(v.w - mx);
    }
    redm[tid] = mx; reds[tid] = se; __syncthreads();
    for (int s2 = 128; s2 > 0; s2 >>= 1) {
        if (tid < s2) {
            const float m2 = redm[tid + s2], sv = reds[tid + s2];
            const float mN = fmaxf(redm[tid], m2);
            reds[tid] = reds[tid] * __expf(redm[tid] - mN) + sv * __expf(m2 - mN);
            redm[tid] = mN;
        }
        __syncthreads();
    }

    if (tid == 0) {
        const int lab = labels[t];
        if (lab >= 0) {
            const float nll = -(row[lab] - redm[0] - logf(reds[0]));
            atomicAdd(&acc[0], nll);
            atomicAdd(&acc[1], 1.0f);
        }
    }
}

__global__ void finalize_kernel(const float* __restrict__ acc, float* __restrict__ out)
{
    out[0] = (acc[1] > 0.f) ? acc[0] / acc[1] : 0.f;
}

// ---------------------------------------------------------------------------
extern "C" void kernel_launch(void* const* d_in, const int* in_sizes, int n_in,
                              void* d_out, int out_size, void* d_ws, size_t ws_size,
                              hipStream_t stream)
{
    const int*   input_ids = (const int*)  d_in[0];
    const int*   labels    = (const int*)  d_in[1];
    const float* word_emb  = (const float*)d_in[2];
    const float* pos_emb   = (const float*)d_in[3];
    const float* type_emb  = (const float*)d_in[4];
    const float* emb_ln_g  = (const float*)d_in[5];
    const float* emb_ln_b  = (const float*)d_in[6];
    const float* Wq = (const float*)d_in[7];   const float* bq = (const float*)d_in[8];
    const float* Wk = (const float*)d_in[9];   const float* bk = (const float*)d_in[10];
    const float* Wv = (const float*)d_in[11];  const float* bv = (const float*)d_in[12];
    const float* Wo = (const float*)d_in[13];  const float* bo = (const float*)d_in[14];
    const float* ln1_g = (const float*)d_in[15]; const float* ln1_b = (const float*)d_in[16];
    const float* W1 = (const float*)d_in[17];  const float* bf1 = (const float*)d_in[18];
    const float* W2 = (const float*)d_in[19];  const float* bf2 = (const float*)d_in[20];
    const float* ln2_g = (const float*)d_in[21]; const float* ln2_b = (const float*)d_in[22];
    const float* Wc = (const float*)d_in[23];  const float* bc = (const float*)d_in[24];

    // ---- workspace layout (fp32 first, then bf16) ----
    float* fws  = (float*)d_ws;
    float* part = fws;                        // split-K partials, <= 3*4096*768 f
    float* lg   = fws;                        // alias: 384*21128 f (head logits)
    float* bqkv = fws + (size_t)TT * QKVN + (size_t)TT * HH;   // 12*2304
    float* acc  = bqkv + (size_t)LL * QKVN;   // 2 (+pad)

    __hip_bfloat16* bws = (__hip_bfloat16*)(acc + 8);
    __hip_bfloat16* h    = bws;                                   // 4096*768
    __hip_bfloat16* ctx  = h    + (size_t)TT * HH;                // 4096*768
    __hip_bfloat16* ff1  = ctx  + (size_t)TT * HH;                // 4096*3072
    __hip_bfloat16* qkvb = ff1;   // alias: qkv bf16 [4096*2304] (disjoint lifetime)
    __hip_bfloat16* qkvw = ff1  + (size_t)TT * FFF;               // 12*2304*768
    __hip_bfloat16* wot  = qkvw + (size_t)LL * QKVN * HH;         // 12*768*768
    __hip_bfloat16* w1t  = wot  + (size_t)LL * HH * HH;           // 12*3072*768
    __hip_bfloat16* w2t  = w1t  + (size_t)LL * FFF * HH;          // 12*768*3072
    __hip_bfloat16* wct  = w2t  + (size_t)LL * HH * FFF;          // 21248*768

    hipMemsetAsync(acc, 0, 2 * sizeof(float), stream);

    // ---- weight convert + transpose (bf16, K-contiguous) ----
    const dim3 tb(32, 8);
    transpose_cvt<<<dim3(24, 24, LL), tb, 0, stream>>>(Wq, qkvw, HH, HH,
        (long long)HH * HH, (long long)QKVN * HH, 0, HH);
    transpose_cvt<<<dim3(24, 24, LL), tb, 0, stream>>>(Wk, qkvw, HH, HH,
        (long long)HH * HH, (long long)QKVN * HH, HH, HH);
    transpose_cvt<<<dim3(24, 24, LL), tb, 0, stream>>>(Wv, qkvw, HH, HH,
        (long long)HH * HH, (long long)QKVN * HH, 2 * HH, HH);
    transpose_cvt<<<dim3(24, 24, LL), tb, 0, stream>>>(Wo, wot, HH, HH,
        (long long)HH * HH, (long long)HH * HH, 0, HH);
    transpose_cvt<<<dim3(96, 24, LL), tb, 0, stream>>>(W1, w1t, HH, FFF,
        (long long)HH * FFF, (long long)FFF * HH, 0, HH);
    transpose_cvt<<<dim3(24, 96, LL), tb, 0, stream>>>(W2, w2t, FFF, HH,
        (long long)FFF * HH, (long long)HH * FFF, 0, FFF);
    transpose_cvt<<<dim3(661, 24, 1), tb, 0, stream>>>(Wc, wct, HH, VV,
        0, 0, 0, HH);
    concat_bias<<<(LL * QKVN + 255) / 256, 256, 0, stream>>>(bq, bk, bv, bqkv);

    // ---- embeddings ----
    embed_ln<<<TT, 256, 0, stream>>>(input_ids, word_emb, pos_emb, type_emb,
                                     emb_ln_g, emb_ln_b, h);

    const dim3 gQKV(QKVN / 128, TT / 128, 1);   // 18 x 32
    const dim3 gWo (HH / 128,  TT / 128, 2);    // 6 x 32 x 2  (split-K=2, Kc=384)
    const dim3 gF  (FFF / 128, TT / 128, 1);    // 24 x 32
    const dim3 gFF2(HH / 128,  TT / 128, 3);    // 6 x 32 x 3  (split-K=3, Kc=1024)
    const dim3 gAttn(SS / 128, NHH, BB);        // 4 x 12 x 8

    for (int l = 0; l < LL; ++l) {
        // QKV projection -> bf16 (Q/K/V are consumed as bf16 by attention anyway)
        gemm_mfma<<<gQKV, 256, 0, stream>>>(h, qkvw + (size_t)l * QKVN * HH,
            bqkv + (size_t)l * QKVN, nullptr, qkvb, TT, QKVN, HH, 0);

        attn_mfma<<<gAttn, 256, 0, stream>>>(qkvb, ctx);

        // ctx @ Wo^T -> 2 fp32 partials
        gemm_mfma<<<gWo, 256, 0, stream>>>(ctx, wot + (size_t)l * HH * HH,
            nullptr, part, nullptr, TT, HH, HH, 0);
        add_ln<<<TT, 256, 0, stream>>>(h, part, 2, bo + (size_t)l * HH,
            ln1_g + (size_t)l * HH, ln1_b + (size_t)l * HH, h);

        // FF1 (overwrites qkvb alias; qkv is dead by now)
        gemm_mfma<<<gF, 256, 0, stream>>>(h, w1t + (size_t)l * FFF * HH,
            bf1 + (size_t)l * FFF, nullptr, ff1, TT, FFF, HH, 1);

        // ff1 @ W2^T -> 3 fp32 partials
        gemm_mfma<<<gFF2, 256, 0, stream>>>(ff1, w2t + (size_t)l * HH * FFF,
            nullptr, part, nullptr, TT, HH, FFF, 0);
        add_ln<<<TT, 256, 0, stream>>>(h, part, 3, bf2 + (size_t)l * HH,
            ln2_g + (size_t)l * HH, ln2_b + (size_t)l * HH, h);
    }

    // ---- LM head + CE per batch (only s >= PROMPT rows) ----
    const int Mchunk = SS - PROMPT;              // 384
    const dim3 gV(VVP / 128, Mchunk / 128, 1);   // 166 x 3
    for (int b = 0; b < BB; ++b) {
        const __hip_bfloat16* Arow = h + (size_t)(b * SS + PROMPT) * HH;
        gemm_mfma<<<gV, 256, 0, stream>>>(Arow, wct, bc, lg, nullptr, Mchunk, VV, HH, 0);
        ce_kernel<<<Mchunk, 256, 0, stream>>>(lg, labels, b, acc);
    }

    finalize_kernel<<<1, 1, 0, stream>>>(acc, (float*)d_out);
}